// Round 2
// baseline (1116.880 us; speedup 1.0000x reference)
//
#include <hip/hip_runtime.h>

namespace {

constexpr int Hn = 16;
constexpr int Sn = 2048;
constexpr int Dn = 128;
constexpr int BM = 64;          // q rows per workgroup
constexpr int BN = 64;          // k cols per tile
constexpr int THREADS = 256;    // 4 waves
constexpr long long OUT0 = 4LL * 16 * 2048 * 128;  // attn_output elems before weights

constexpr int QSTR = 136;  // shorts per row of qlds/klds (128 elems + 8 pad)
constexpr int VSTR = 68;   // shorts per row of vtlds/wlds (64 elems + 4 pad)

typedef short s16x4 __attribute__((ext_vector_type(4)));
typedef float f32x4 __attribute__((ext_vector_type(4)));

__device__ __forceinline__ unsigned short f2b(float x) {
    union { float f; unsigned u; } v; v.f = x;
    return (unsigned short)((v.u + 0x7FFFu + ((v.u >> 16) & 1u)) >> 16);  // RNE
}

// 64x128 fp32 tile (row stride 128) -> bf16 LDS rows, row stride QSTR shorts
__device__ __forceinline__ void stage_rows(const float* __restrict__ g,
                                           unsigned short* lds, int tid) {
    const int c  = tid & 15;
    const int r0 = tid >> 4;
#pragma unroll
    for (int it = 0; it < 4; ++it) {
        const int r = r0 + 16 * it;
        const float4* gp = reinterpret_cast<const float4*>(g + (size_t)r * Dn + c * 8);
        const float4 f0 = gp[0];
        const float4 f1 = gp[1];
        uint4 u;
        u.x = (unsigned)f2b(f0.x) | ((unsigned)f2b(f0.y) << 16);
        u.y = (unsigned)f2b(f0.z) | ((unsigned)f2b(f0.w) << 16);
        u.z = (unsigned)f2b(f1.x) | ((unsigned)f2b(f1.y) << 16);
        u.w = (unsigned)f2b(f1.z) | ((unsigned)f2b(f1.w) << 16);
        *reinterpret_cast<uint4*>(reinterpret_cast<char*>(lds) + r * (QSTR * 2) + c * 16) = u;
    }
}

// V tile 64x128 fp32 -> vt[d][k] bf16, row stride VSTR shorts
__device__ __forceinline__ void stage_vt(const float* __restrict__ g,
                                         unsigned short* vt, int tid) {
    const int tc = tid & 31;   // d chunk of 4
    const int kp = tid >> 5;   // 0..7
#pragma unroll
    for (int it = 0; it < 4; ++it) {
        const int kr = 2 * (kp + 8 * it);
        const float4 a = *reinterpret_cast<const float4*>(g + (size_t)kr * Dn + 4 * tc);
        const float4 b = *reinterpret_cast<const float4*>(g + (size_t)(kr + 1) * Dn + 4 * tc);
        const float av[4] = {a.x, a.y, a.z, a.w};
        const float bv[4] = {b.x, b.y, b.z, b.w};
#pragma unroll
        for (int j = 0; j < 4; ++j) {
            const int d = 4 * tc + j;
            const unsigned w = (unsigned)f2b(av[j]) | ((unsigned)f2b(bv[j]) << 16);
            *reinterpret_cast<unsigned*>(reinterpret_cast<char*>(vt) + d * (VSTR * 2) + kr * 2) = w;
        }
    }
}

struct SAcc { f32x4 t[4]; };

__global__ __launch_bounds__(THREADS)
void attn_fused(const float* __restrict__ Q, const float* __restrict__ K,
                const float* __restrict__ V, const int* __restrict__ M,
                float* __restrict__ out) {
    __shared__ __align__(16) unsigned short qlds[BM * QSTR];
    __shared__ __align__(16) unsigned short klds[BN * QSTR];
    __shared__ __align__(16) unsigned short vtlds[Dn * VSTR];
    __shared__ __align__(16) unsigned short wlds[BM * VSTR];
    __shared__ float rsum[BM];

    const int tid  = threadIdx.x;
    const int lane = tid & 63;
    const int wv   = tid >> 6;
    const int lr   = lane & 15;
    const int lg   = lane >> 4;

    const int bh    = blockIdx.y;
    const int b     = bh >> 4;               // H = 16
    const int qbase = blockIdx.x * BM;

    const float* Qg = Q + ((size_t)bh * Sn + qbase) * Dn;
    const float* Kg = K + (size_t)bh * Sn * Dn;
    const float* Vg = V + (size_t)bh * Sn * Dn;
    const int*   Mg = M + ((size_t)b * Sn + qbase) * Sn;
    float*       Og = out + ((size_t)bh * Sn + qbase) * Dn;
    float*       Wg = out + OUT0 + ((size_t)bh * Sn + qbase) * Sn;

    const float scl2 = 1.4426950408889634f / 11.313708498984761f; // log2(e)/sqrt(D)
    const int qrow = 16 * wv + 4 * lg;   // lane's S-result rows are qrow+r, cols 16t+lr

    stage_rows(Qg, qlds, tid);

    const f32x4 zero = {0.f, 0.f, 0.f, 0.f};

    auto qk_tile = [&]() -> SAcc {
        SAcc s;
#pragma unroll
        for (int t = 0; t < 4; ++t) s.t[t] = zero;
#pragma unroll
        for (int dsv = 0; dsv < 8; ++dsv) {
            const int koff = dsv * 32 + lg * 8;   // bytes: k = dsv*16 + lg*4 + e
            const s16x4 a = *reinterpret_cast<const s16x4*>(
                reinterpret_cast<const char*>(qlds) + (16 * wv + lr) * (QSTR * 2) + koff);
#pragma unroll
            for (int t = 0; t < 4; ++t) {
                const s16x4 bb = *reinterpret_cast<const s16x4*>(
                    reinterpret_cast<const char*>(klds) + (16 * t + lr) * (QSTR * 2) + koff);
                s.t[t] = __builtin_amdgcn_mfma_f32_16x16x16bf16_1k(a, bb, s.t[t], 0, 0, 0);
            }
        }
        return s;
    };

    // ---------------- pass A: row sums of exp ----------------
    float rs[4] = {0.f, 0.f, 0.f, 0.f};
    for (int k0 = 0; k0 < Sn; k0 += BN) {
        __syncthreads();
        stage_rows(Kg + (size_t)k0 * Dn, klds, tid);
        __syncthreads();
        SAcc s = qk_tile();
#pragma unroll
        for (int t = 0; t < 4; ++t) {
            const int kg = k0 + 16 * t + lr;
#pragma unroll
            for (int r = 0; r < 4; ++r) {
                const int mv = Mg[(size_t)(qrow + r) * Sn + kg];
                rs[r] += mv ? exp2f(s.t[t][r] * scl2) : 0.f;
            }
        }
    }
#pragma unroll
    for (int r = 0; r < 4; ++r) {
        float v = rs[r];
        v += __shfl_xor(v, 1);
        v += __shfl_xor(v, 2);
        v += __shfl_xor(v, 4);
        v += __shfl_xor(v, 8);
        if (lr == 0) rsum[qrow + r] = v;
    }
    __syncthreads();
    float inv[4];
#pragma unroll
    for (int r = 0; r < 4; ++r) inv[r] = 1.0f / rsum[qrow + r];

    // ---------------- pass B: weights + PV ----------------
    f32x4 oacc[8];
#pragma unroll
    for (int f = 0; f < 8; ++f) oacc[f] = zero;

    for (int k0 = 0; k0 < Sn; k0 += BN) {
        __syncthreads();
        stage_rows(Kg + (size_t)k0 * Dn, klds, tid);
        stage_vt(Vg + (size_t)k0 * Dn, vtlds, tid);
        __syncthreads();

        SAcc s = qk_tile();

#pragma unroll
        for (int t = 0; t < 4; ++t) {
            const int kg = k0 + 16 * t + lr;
#pragma unroll
            for (int r = 0; r < 4; ++r) {
                const int mv = Mg[(size_t)(qrow + r) * Sn + kg];
                const float e = mv ? exp2f(s.t[t][r] * scl2) : 0.f;
                const float w = e * inv[r];
                Wg[(size_t)(qrow + r) * Sn + kg] = w;
                reinterpret_cast<unsigned short*>(
                    reinterpret_cast<char*>(wlds) + (qrow + r) * (VSTR * 2))[16 * t + lr] = f2b(w);
            }
        }
        __syncthreads();

#pragma unroll
        for (int kk = 0; kk < 4; ++kk) {
            const int koff = kk * 32 + lg * 8;   // bytes: k = kk*16 + lg*4 + e
            const s16x4 aw = *reinterpret_cast<const s16x4*>(
                reinterpret_cast<const char*>(wlds) + (16 * wv + lr) * (VSTR * 2) + koff);
#pragma unroll
            for (int f = 0; f < 8; ++f) {
                const s16x4 bv = *reinterpret_cast<const s16x4*>(
                    reinterpret_cast<const char*>(vtlds) + (16 * f + lr) * (VSTR * 2) + koff);
                oacc[f] = __builtin_amdgcn_mfma_f32_16x16x16bf16_1k(aw, bv, oacc[f], 0, 0, 0);
            }
        }
    }

#pragma unroll
    for (int f = 0; f < 8; ++f) {
#pragma unroll
        for (int r = 0; r < 4; ++r) {
            Og[(size_t)(qrow + r) * Dn + 16 * f + lr] = oacc[f][r];
        }
    }
}

} // namespace

extern "C" void kernel_launch(void* const* d_in, const int* in_sizes, int n_in,
                              void* d_out, int out_size, void* d_ws, size_t ws_size,
                              hipStream_t stream) {
    (void)in_sizes; (void)n_in; (void)d_ws; (void)ws_size; (void)out_size;
    const float* Q = (const float*)d_in[0];
    const float* K = (const float*)d_in[1];
    const float* V = (const float*)d_in[2];
    const int*   M = (const int*)d_in[3];
    float* out = (float*)d_out;
    dim3 grid(Sn / BM, 4 * Hn);   // (q tiles, B*H)
    attn_fused<<<grid, THREADS, 0, stream>>>(Q, K, V, M, out);
}

// Round 3
// 1005.676 us; speedup vs baseline: 1.1106x; 1.1106x over previous
//
#include <hip/hip_runtime.h>
#include <hip/hip_bf16.h>

namespace {

constexpr int Hn = 16;
constexpr int Sn = 2048;
constexpr int Dn = 128;
constexpr int BM = 64;          // q rows per workgroup
constexpr int BN = 64;          // k cols per tile
constexpr int THREADS = 256;    // 4 waves
constexpr int NT = Sn / BN;     // 32 k-tiles
constexpr long long OUT0 = 4LL * 16 * 2048 * 128;  // attn_output elems before weights

constexpr int QSTR = 136;  // shorts per row of K/Q LDS tiles (128 + 8 pad)
constexpr int VSTR = 68;   // shorts per row of vt/w LDS tiles (64 + 4 pad)

typedef short s16x4 __attribute__((ext_vector_type(4)));
typedef float f32x4 __attribute__((ext_vector_type(4)));

__device__ __forceinline__ unsigned short f2bu(float x) {
    return __bfloat16_as_ushort(__float2bfloat16(x));   // RNE, compiler fuses to v_cvt_pk
}
__device__ __forceinline__ unsigned pk2(float lo, float hi) {
    return (unsigned)f2bu(lo) | ((unsigned)f2bu(hi) << 16);
}

// ---- K/Q staging: 64x128 f32 -> bf16 rows (QSTR stride). Lane (sc,sr). ----
__device__ __forceinline__ void k_issue(const float* __restrict__ g, int sc, int sr,
                                        float4* v) {
#pragma unroll
    for (int it = 0; it < 4; ++it) {
        const float4* gp = reinterpret_cast<const float4*>(
            g + (size_t)(sr + 16 * it) * Dn + sc * 8);
        v[2 * it]     = gp[0];
        v[2 * it + 1] = gp[1];
    }
}
__device__ __forceinline__ void k_write(unsigned short* lds, int sc, int sr,
                                        const float4* v) {
#pragma unroll
    for (int it = 0; it < 4; ++it) {
        const int r = sr + 16 * it;
        uint4 u;
        u.x = pk2(v[2 * it].x,     v[2 * it].y);
        u.y = pk2(v[2 * it].z,     v[2 * it].w);
        u.z = pk2(v[2 * it + 1].x, v[2 * it + 1].y);
        u.w = pk2(v[2 * it + 1].z, v[2 * it + 1].w);
        *reinterpret_cast<uint4*>(reinterpret_cast<char*>(lds) + r * (QSTR * 2) + sc * 16) = u;
    }
}

// ---- V staging: 64x128 f32 -> vt[d][k] bf16 (VSTR stride). Lane (tc,kp). ----
__device__ __forceinline__ void v_issue(const float* __restrict__ g, int tc, int kp,
                                        float4* v) {
#pragma unroll
    for (int it = 0; it < 4; ++it) {
        const int kr = 2 * (kp + 8 * it);
        v[2 * it]     = *reinterpret_cast<const float4*>(g + (size_t)kr * Dn + 4 * tc);
        v[2 * it + 1] = *reinterpret_cast<const float4*>(g + (size_t)(kr + 1) * Dn + 4 * tc);
    }
}
__device__ __forceinline__ void v_write(unsigned short* vt, int tc, int kp,
                                        const float4* v) {
#pragma unroll
    for (int it = 0; it < 4; ++it) {
        const int kr = 2 * (kp + 8 * it);
        const float a4[4] = {v[2 * it].x, v[2 * it].y, v[2 * it].z, v[2 * it].w};
        const float b4[4] = {v[2 * it + 1].x, v[2 * it + 1].y, v[2 * it + 1].z, v[2 * it + 1].w};
#pragma unroll
        for (int j = 0; j < 4; ++j) {
            const int d = 4 * tc + j;
            *reinterpret_cast<unsigned*>(reinterpret_cast<char*>(vt) + d * (VSTR * 2) + kr * 2)
                = pk2(a4[j], b4[j]);
        }
    }
}

struct SAcc { f32x4 t[4]; };

__global__ __launch_bounds__(THREADS)
void attn_fused(const float* __restrict__ Q, const float* __restrict__ K,
                const float* __restrict__ V, const int* __restrict__ M,
                float* __restrict__ out) {
    // bufA: K tile (QSTR rows). bufB: Q stage / pass-A K double-buffer / pass-B vt.
    // wlds: bf16 weight tile for PV A-operand.
    __shared__ __align__(16) unsigned short smem[8704 * 2 + BM * VSTR];
    unsigned short* bufA = smem;
    unsigned short* bufB = smem + 8704;
    unsigned short* wlds = smem + 17408;

    const int tid  = threadIdx.x;
    const int lane = tid & 63;
    const int wv   = tid >> 6;
    const int lr   = lane & 15;
    const int lg   = lane >> 4;

    const int bh    = blockIdx.y;
    const int b     = bh >> 4;               // H = 16
    const int qbase = blockIdx.x * BM;

    const float* Qg = Q + ((size_t)bh * Sn + qbase) * Dn;
    const float* Kg = K + (size_t)bh * Sn * Dn;
    const float* Vg = V + (size_t)bh * Sn * Dn;
    const int*   Mg = M + ((size_t)b * Sn + qbase) * Sn;
    float*       Og = out + ((size_t)bh * Sn + qbase) * Dn;
    float*       Wg = out + OUT0 + ((size_t)bh * Sn + qbase) * Sn;

    const float scl2 = 1.4426950408889634f / 11.313708498984761f; // log2(e)/sqrt(D)
    const int qrow = 16 * wv + 4 * lg;   // lane's S rows are qrow+r, cols 16t+lr

    const int sc = tid & 15, sr = tid >> 4;   // K/Q staging lane map
    const int tc = tid & 31, kp = tid >> 5;   // V staging lane map

    const int* mrow[4];
#pragma unroll
    for (int r = 0; r < 4; ++r) mrow[r] = Mg + (size_t)(qrow + r) * Sn + lr;

    // ---------- prologue: Q -> bufB, K0 -> bufA; Q frags to regs ----------
    {
        float4 qv[8], kv[8];
        k_issue(Qg, sc, sr, qv);
        k_issue(Kg, sc, sr, kv);
        k_write(bufB, sc, sr, qv);
        k_write(bufA, sc, sr, kv);
    }
    __syncthreads();
    s16x4 qf[8];
#pragma unroll
    for (int dsv = 0; dsv < 8; ++dsv)
        qf[dsv] = *reinterpret_cast<const s16x4*>(
            reinterpret_cast<const char*>(bufB) + (16 * wv + lr) * (QSTR * 2) + dsv * 32 + lg * 8);
    __syncthreads();

    const f32x4 zero = {0.f, 0.f, 0.f, 0.f};

    auto qk_tile = [&](const unsigned short* kb) -> SAcc {
        SAcc s;
#pragma unroll
        for (int t = 0; t < 4; ++t) s.t[t] = zero;
#pragma unroll
        for (int dsv = 0; dsv < 8; ++dsv) {
            const int koff = dsv * 32 + lg * 8;   // k = dsv*16 + lg*4 + e
#pragma unroll
            for (int t = 0; t < 4; ++t) {
                const s16x4 bb = *reinterpret_cast<const s16x4*>(
                    reinterpret_cast<const char*>(kb) + (16 * t + lr) * (QSTR * 2) + koff);
                s.t[t] = __builtin_amdgcn_mfma_f32_16x16x16bf16_1k(qf[dsv], bb, s.t[t], 0, 0, 0);
            }
        }
        return s;
    };

    // ---------------- pass A: row sums of exp (K double-buffered) ----------------
    float rs[4] = {0.f, 0.f, 0.f, 0.f};
    for (int t = 0; t < NT; ++t) {
        unsigned short* cur = (t & 1) ? bufB : bufA;
        unsigned short* nxt = (t & 1) ? bufA : bufB;
        float4 kv[8];
        const bool pre = (t + 1 < NT);
        if (pre) k_issue(Kg + (size_t)(t + 1) * BN * Dn, sc, sr, kv);

        int mv[16];
        const int kc = t * BN;
#pragma unroll
        for (int tt = 0; tt < 4; ++tt)
#pragma unroll
            for (int r = 0; r < 4; ++r) mv[4 * tt + r] = mrow[r][kc + 16 * tt];

        SAcc s = qk_tile(cur);
#pragma unroll
        for (int tt = 0; tt < 4; ++tt)
#pragma unroll
            for (int r = 0; r < 4; ++r)
                rs[r] += mv[4 * tt + r] ? __builtin_amdgcn_exp2f(s.t[tt][r] * scl2) : 0.f;

        if (pre) k_write(nxt, sc, sr, kv);
        __syncthreads();
    }

    // butterfly over lr bits leaves the full 16-lane sum in EVERY lane
    float inv[4];
#pragma unroll
    for (int r = 0; r < 4; ++r) {
        float v = rs[r];
        v += __shfl_xor(v, 1);
        v += __shfl_xor(v, 2);
        v += __shfl_xor(v, 4);
        v += __shfl_xor(v, 8);
        inv[r] = 1.0f / v;
    }

    // ---------------- pass B prologue: K0 -> bufA, V0^T -> bufB ----------------
    {
        float4 kv0[8], vv0[8];
        k_issue(Kg, sc, sr, kv0);
        v_issue(Vg, tc, kp, vv0);
        k_write(bufA, sc, sr, kv0);
        v_write(bufB, tc, kp, vv0);
    }
    __syncthreads();

    // ---------------- pass B: weights + PV ----------------
    f32x4 oacc[8];
#pragma unroll
    for (int f = 0; f < 8; ++f) oacc[f] = zero;

    for (int t = 0; t < NT; ++t) {
        float4 kv[8], vv[8];
        const bool pre = (t + 1 < NT);
        if (pre) {
            k_issue(Kg + (size_t)(t + 1) * BN * Dn, sc, sr, kv);
            v_issue(Vg + (size_t)(t + 1) * BN * Dn, tc, kp, vv);
        }

        int mv[16];
        const int kc = t * BN;
#pragma unroll
        for (int tt = 0; tt < 4; ++tt)
#pragma unroll
            for (int r = 0; r < 4; ++r) mv[4 * tt + r] = mrow[r][kc + 16 * tt];

        SAcc s = qk_tile(bufA);

#pragma unroll
        for (int tt = 0; tt < 4; ++tt) {
#pragma unroll
            for (int r = 0; r < 4; ++r) {
                const float e = mv[4 * tt + r] ? __builtin_amdgcn_exp2f(s.t[tt][r] * scl2) : 0.f;
                const float w = e * inv[r];
                Wg[(size_t)(qrow + r) * Sn + kc + 16 * tt + lr] = w;
                reinterpret_cast<unsigned short*>(
                    reinterpret_cast<char*>(wlds) + (qrow + r) * (VSTR * 2))[16 * tt + lr] = f2bu(w);
            }
        }
        // no barrier: each wave reads only its own 16 wlds rows (intra-wave dep)

#pragma unroll
        for (int kk = 0; kk < 4; ++kk) {
            const int koff = kk * 32 + lg * 8;   // k = kk*16 + lg*4 + e
            const s16x4 aw = *reinterpret_cast<const s16x4*>(
                reinterpret_cast<const char*>(wlds) + (16 * wv + lr) * (VSTR * 2) + koff);
#pragma unroll
            for (int f = 0; f < 8; ++f) {
                const s16x4 bv = *reinterpret_cast<const s16x4*>(
                    reinterpret_cast<const char*>(bufB) + (16 * f + lr) * (VSTR * 2) + koff);
                oacc[f] = __builtin_amdgcn_mfma_f32_16x16x16bf16_1k(aw, bv, oacc[f], 0, 0, 0);
            }
        }
        __syncthreads();          // all waves done reading bufA/bufB tile t
        if (pre) {
            k_write(bufA, sc, sr, kv);
            v_write(bufB, tc, kp, vv);
        }
        __syncthreads();          // tile t+1 visible
    }

#pragma unroll
    for (int f = 0; f < 8; ++f) {
#pragma unroll
        for (int r = 0; r < 4; ++r) {
            Og[(size_t)(qrow + r) * Dn + 16 * f + lr] = oacc[f][r];
        }
    }
}

} // namespace

extern "C" void kernel_launch(void* const* d_in, const int* in_sizes, int n_in,
                              void* d_out, int out_size, void* d_ws, size_t ws_size,
                              hipStream_t stream) {
    (void)in_sizes; (void)n_in; (void)d_ws; (void)ws_size; (void)out_size;
    const float* Q = (const float*)d_in[0];
    const float* K = (const float*)d_in[1];
    const float* V = (const float*)d_in[2];
    const int*   M = (const int*)d_in[3];
    float* out = (float*)d_out;
    dim3 grid(Sn / BM, 4 * Hn);   // (q tiles, B*H)
    attn_fused<<<grid, THREADS, 0, stream>>>(Q, K, V, M, out);
}